// Round 4
// baseline (32.226 us; speedup 1.0000x reference)
//
#include <hip/hip_runtime.h>

// LengthRegulator: B=32, L=256, H=384, T(MAX_WAVE)=2048
// out0: (B, H, T) float32 = gathered^T ; out1: (B, T) float32 mask
constexpr int Lc = 256;
constexpr int Hc = 384;
constexpr int Tc = 2048;
constexpr int Bc = 32;
constexpr int T_PER_BLOCK = 1024;  // 256 threads x 4 t each (float4 stores)
constexpr int H_TILE = 16;         // 384 / 16 = 24 h-tiles -> grid (2,24,32)=1536 blocks
constexpr int PADW = 17;           // LDS row stride (floats); 17 coprime 32 banks

// ---------------- K1: per-batch scan + searchsorted -> idx table + mask ----
// grid = 32 blocks (one per batch), 256 threads. Writes:
//   idx16[b][t] = safe_idx | (valid ? 0 : 0x8000)   (ushort)
//   mask[b][t]  = valid ? 1.0f : 0.0f
__global__ __launch_bounds__(256) void lr_index_kernel(
    const int*      __restrict__ dur,    // (B, L)
    unsigned short* __restrict__ idx16,  // (B, T)
    float*          __restrict__ mask)   // (B, T)
{
    const int tid = threadIdx.x;
    const int b   = blockIdx.x;

    __shared__ int s_csum[Lc];
    s_csum[tid] = dur[b * Lc + tid];
    __syncthreads();
#pragma unroll
    for (int off = 1; off < Lc; off <<= 1) {
        int v = (tid >= off) ? s_csum[tid - off] : 0;
        __syncthreads();
        s_csum[tid] += v;
        __syncthreads();
    }
    const int total = s_csum[Lc - 1];

    // each thread handles 8 consecutive t: one binary search + linear advance
    const int t0 = tid * 8;
    int lo = 0, hi = Lc;
    while (lo < hi) {
        int mid = (lo + hi) >> 1;
        if (s_csum[mid] <= t0) lo = mid + 1; else hi = mid;
    }
    int cur = lo;

    unsigned int packed[4];
    float mv[8];
#pragma unroll
    for (int p = 0; p < 4; ++p) {
        unsigned int w = 0;
#pragma unroll
        for (int q = 0; q < 2; ++q) {
            const int k  = p * 2 + q;
            const int tt = t0 + k;
            while (cur < Lc && s_csum[cur] <= tt) cur++;
            const int safe  = (cur < Lc - 1) ? cur : (Lc - 1);
            const bool valid = (tt < total);
            unsigned int enc = (unsigned int)safe | (valid ? 0u : 0x8000u);
            w |= enc << (16 * q);
            mv[k] = valid ? 1.0f : 0.0f;
        }
        packed[p] = w;
    }

    // 16B idx store + 2x16B mask stores, all coalesced
    uint4 iv; iv.x = packed[0]; iv.y = packed[1]; iv.z = packed[2]; iv.w = packed[3];
    *reinterpret_cast<uint4*>(idx16 + (size_t)b * Tc + t0) = iv;
    float4 m0; m0.x = mv[0]; m0.y = mv[1]; m0.z = mv[2]; m0.w = mv[3];
    float4 m1; m1.x = mv[4]; m1.y = mv[5]; m1.z = mv[6]; m1.w = mv[7];
    *reinterpret_cast<float4*>(mask + (size_t)b * Tc + t0)     = m0;
    *reinterpret_cast<float4*>(mask + (size_t)b * Tc + t0 + 4) = m1;
}

// ---------------- K2: pure expand (no scan, one barrier) -------------------
__global__ __launch_bounds__(256) void lr_expand_kernel(
    const float*          __restrict__ enc,    // (B, L, H)
    const unsigned short* __restrict__ idx16,  // (B, T)
    float*                __restrict__ out)    // (B, H, T)
{
    const int tid = threadIdx.x;
    const int b   = blockIdx.z;
    const int h0  = blockIdx.y * H_TILE;

    __shared__ float s_enc[Lc * PADW];

    // stage enc tile (256 rows x 16 cols), coalesced 64B-per-row float4 loads
    {
        const float* encb = enc + (size_t)b * (Lc * Hc) + h0;
        const int r  = tid >> 2;          // 0..63
        const int c4 = (tid & 3) * 4;     // 0,4,8,12
#pragma unroll
        for (int it = 0; it < 4; ++it) {
            const int row = r + it * 64;
            float4 v = *reinterpret_cast<const float4*>(encb + (size_t)row * Hc + c4);
            float* dst = s_enc + row * PADW + c4;
            dst[0] = v.x; dst[1] = v.y; dst[2] = v.z; dst[3] = v.w;
        }
    }

    // precomputed indices: 4 t's per thread, one 8B load
    const int tbase = blockIdx.x * T_PER_BLOCK + tid * 4;
    ushort4 iv = *reinterpret_cast<const ushort4*>(idx16 + (size_t)b * Tc + tbase);

    int   rowoff[4];
    float mflag[4];
    rowoff[0] = (int)(iv.x & 0xff) * PADW; mflag[0] = (iv.x & 0x8000) ? 0.0f : 1.0f;
    rowoff[1] = (int)(iv.y & 0xff) * PADW; mflag[1] = (iv.y & 0x8000) ? 0.0f : 1.0f;
    rowoff[2] = (int)(iv.z & 0xff) * PADW; mflag[2] = (iv.z & 0x8000) ? 0.0f : 1.0f;
    rowoff[3] = (int)(iv.w & 0xff) * PADW; mflag[3] = (iv.w & 0x8000) ? 0.0f : 1.0f;

    __syncthreads();  // the ONLY barrier

    float* outb = out + (size_t)b * (Hc * Tc) + (size_t)h0 * Tc + tbase;
#pragma unroll
    for (int hh = 0; hh < H_TILE; ++hh) {
        float4 v;
        v.x = s_enc[rowoff[0] + hh] * mflag[0];
        v.y = s_enc[rowoff[1] + hh] * mflag[1];
        v.z = s_enc[rowoff[2] + hh] * mflag[2];
        v.w = s_enc[rowoff[3] + hh] * mflag[3];
        *reinterpret_cast<float4*>(outb + (size_t)hh * Tc) = v;
    }
}

// ---------------- fallback: round-3 fused kernel (if ws too small) ---------
__global__ __launch_bounds__(256) void lr_fused_kernel(
    const float* __restrict__ enc, const int* __restrict__ dur,
    float* __restrict__ out, float* __restrict__ mask)
{
    const int tid = threadIdx.x;
    const int b   = blockIdx.z;
    const int h0  = blockIdx.y * H_TILE;

    __shared__ int   s_csum[Lc];
    __shared__ float s_enc[Lc * PADW];

    {
        const float* encb = enc + (size_t)b * (Lc * Hc) + h0;
        const int r  = tid >> 2;
        const int c4 = (tid & 3) * 4;
#pragma unroll
        for (int it = 0; it < 4; ++it) {
            const int row = r + it * 64;
            float4 v = *reinterpret_cast<const float4*>(encb + (size_t)row * Hc + c4);
            float* dst = s_enc + row * PADW + c4;
            dst[0] = v.x; dst[1] = v.y; dst[2] = v.z; dst[3] = v.w;
        }
    }

    s_csum[tid] = dur[b * Lc + tid];
    __syncthreads();
#pragma unroll
    for (int off = 1; off < Lc; off <<= 1) {
        int v = (tid >= off) ? s_csum[tid - off] : 0;
        __syncthreads();
        s_csum[tid] += v;
        __syncthreads();
    }
    const int total = s_csum[Lc - 1];

    const int tbase = blockIdx.x * T_PER_BLOCK + tid * 4;
    int   rowoff[4];
    float mflag[4];
    {
        int lo = 0, hi = Lc;
        while (lo < hi) {
            int mid = (lo + hi) >> 1;
            if (s_csum[mid] <= tbase) lo = mid + 1; else hi = mid;
        }
        int cur = lo;
#pragma unroll
        for (int k = 0; k < 4; ++k) {
            const int tt = tbase + k;
            while (cur < Lc && s_csum[cur] <= tt) cur++;
            const int safe = (cur < Lc - 1) ? cur : (Lc - 1);
            rowoff[k] = safe * PADW;
            mflag[k]  = (tt < total) ? 1.0f : 0.0f;
        }
    }

    float* outb = out + (size_t)b * (Hc * Tc) + (size_t)h0 * Tc + tbase;
#pragma unroll
    for (int hh = 0; hh < H_TILE; ++hh) {
        float4 v;
        v.x = s_enc[rowoff[0] + hh] * mflag[0];
        v.y = s_enc[rowoff[1] + hh] * mflag[1];
        v.z = s_enc[rowoff[2] + hh] * mflag[2];
        v.w = s_enc[rowoff[3] + hh] * mflag[3];
        *reinterpret_cast<float4*>(outb + (size_t)hh * Tc) = v;
    }

    if (blockIdx.y == 0) {
        float4 m;
        m.x = mflag[0]; m.y = mflag[1]; m.z = mflag[2]; m.w = mflag[3];
        *reinterpret_cast<float4*>(mask + (size_t)b * Tc + tbase) = m;
    }
}

extern "C" void kernel_launch(void* const* d_in, const int* in_sizes, int n_in,
                              void* d_out, int out_size, void* d_ws, size_t ws_size,
                              hipStream_t stream) {
    const float* enc = (const float*)d_in[0];   // (32, 256, 384) f32
    const int*   dur = (const int*)d_in[1];     // (32, 256) i32

    float* out  = (float*)d_out;                      // (32, 384, 2048)
    float* mask = out + (size_t)Bc * Hc * Tc;         // (32, 2048)

    const size_t idx_bytes = (size_t)Bc * Tc * sizeof(unsigned short);  // 128 KB

    if (ws_size >= idx_bytes) {
        unsigned short* idx16 = (unsigned short*)d_ws;
        lr_index_kernel<<<Bc, 256, 0, stream>>>(dur, idx16, mask);
        dim3 grid(Tc / T_PER_BLOCK, Hc / H_TILE, Bc);  // (2, 24, 32)
        lr_expand_kernel<<<grid, dim3(256), 0, stream>>>(enc, idx16, out);
    } else {
        dim3 grid(Tc / T_PER_BLOCK, Hc / H_TILE, Bc);
        lr_fused_kernel<<<grid, dim3(256), 0, stream>>>(enc, dur, out, mask);
    }
}

// Round 6
// 26.959 us; speedup vs baseline: 1.1954x; 1.1954x over previous
//
#include <hip/hip_runtime.h>

// LengthRegulator: B=32, L=256, H=384, T(MAX_WAVE)=2048
// out0: (B, H, T) float32 = gathered^T ; out1: (B, T) float32 mask
constexpr int Lc = 256;
constexpr int Hc = 384;
constexpr int Tc = 2048;
constexpr int Bc = 32;
constexpr int T_PER_BLOCK = 1024;  // 256 threads x 4 t each (float4 stores)
constexpr int H_TILE = 16;         // 384/16 = 24 h-tiles -> grid (2,24,32)=1536 blocks
constexpr int PADW = 17;           // LDS row stride (floats); 17 coprime 32 banks

typedef float  floatx4 __attribute__((ext_vector_type(4)));

__global__ __launch_bounds__(256) void lr_fused_kernel(
    const float* __restrict__ enc,   // (B, L, H)
    const int*   __restrict__ dur,   // (B, L)
    float*       __restrict__ out,   // (B, H, T)
    float*       __restrict__ mask)  // (B, T)
{
    const int tid  = threadIdx.x;     // 0..255
    const int lane = tid & 63;
    const int wv   = tid >> 6;        // wave 0..3
    const int b    = blockIdx.z;
    const int h0   = blockIdx.y * H_TILE;

    __shared__ float          s_enc[Lc * PADW];  // 17.4 KB
    __shared__ unsigned short s_row[Tc];         // 4 KB: t -> row index
    __shared__ int            s_wtot[4];

    // ---- 1) issue enc-tile staging loads FIRST (longest latency) ----------
    const float* encb = enc + (size_t)b * (Lc * Hc) + h0;
    const int r  = tid >> 2;          // 0..63
    const int c4 = (tid & 3) * 4;     // 0,4,8,12
    floatx4 st[4];
#pragma unroll
    for (int it = 0; it < 4; ++it)
        st[it] = *reinterpret_cast<const floatx4*>(encb + (size_t)(r + it * 64) * Hc + c4);

    // ---- 2) duration load + pre-fill s_row with Lc-1 (=255) ---------------
    const int d = dur[b * Lc + tid];
    {
        uint4 f;
        f.x = 0x00FF00FFu; f.y = 0x00FF00FFu; f.z = 0x00FF00FFu; f.w = 0x00FF00FFu;
        *reinterpret_cast<uint4*>(s_row + tid * 8) = f;   // 8 ushorts/thread
    }

    // ---- 3) barrier-free wave scan of durations ---------------------------
    int s = d;
#pragma unroll
    for (int off = 1; off < 64; off <<= 1) {
        int t = __shfl_up(s, off);
        if (lane >= off) s += t;
    }
    if (lane == 63) s_wtot[wv] = s;

    // write staged enc tile to LDS (overlaps with scan scheduling)
#pragma unroll
    for (int it = 0; it < 4; ++it) {
        float* dst = s_enc + (r + it * 64) * PADW + c4;
        dst[0] = st[it].x; dst[1] = st[it].y; dst[2] = st[it].z; dst[3] = st[it].w;
    }

    __syncthreads();  // barrier #1 (also drains staging vmcnt — unavoidable)

    // ---- 4) cross-wave offsets + scatter row indices ----------------------
    int pre = 0, total = 0;
#pragma unroll
    for (int w = 0; w < 4; ++w) {
        int t = s_wtot[w];
        total += t;
        if (w < wv) pre += t;
    }
    const int csum_i = s + pre;          // inclusive csum at position tid
    const int excl   = csum_i - d;       // exclusive prefix
    int hiw = csum_i; if (hiw > Tc) hiw = Tc;   // clamp to table size
    for (int t = excl; t < hiw; ++t) s_row[t] = (unsigned short)tid;

    __syncthreads();  // barrier #2

    // ---- 5) read 4 precomputed indices, gather from LDS, stream out -------
    const int tbase = blockIdx.x * T_PER_BLOCK + tid * 4;
    ushort4 iv = *reinterpret_cast<const ushort4*>(s_row + tbase);

    int   rowoff[4];
    float mflag[4];
    rowoff[0] = (int)iv.x * PADW; mflag[0] = (tbase + 0 < total) ? 1.0f : 0.0f;
    rowoff[1] = (int)iv.y * PADW; mflag[1] = (tbase + 1 < total) ? 1.0f : 0.0f;
    rowoff[2] = (int)iv.z * PADW; mflag[2] = (tbase + 2 < total) ? 1.0f : 0.0f;
    rowoff[3] = (int)iv.w * PADW; mflag[3] = (tbase + 3 < total) ? 1.0f : 0.0f;

    float* outb = out + (size_t)b * (Hc * Tc) + (size_t)h0 * Tc + tbase;
#pragma unroll
    for (int hh = 0; hh < H_TILE; ++hh) {
        floatx4 v;
        v.x = s_enc[rowoff[0] + hh] * mflag[0];
        v.y = s_enc[rowoff[1] + hh] * mflag[1];
        v.z = s_enc[rowoff[2] + hh] * mflag[2];
        v.w = s_enc[rowoff[3] + hh] * mflag[3];
        __builtin_nontemporal_store(v, reinterpret_cast<floatx4*>(outb + (size_t)hh * Tc));
    }

    // ---- 6) mask (one h-tile writes it) -----------------------------------
    if (blockIdx.y == 0) {
        floatx4 m;
        m.x = mflag[0]; m.y = mflag[1]; m.z = mflag[2]; m.w = mflag[3];
        __builtin_nontemporal_store(m, reinterpret_cast<floatx4*>(mask + (size_t)b * Tc + tbase));
    }
}

extern "C" void kernel_launch(void* const* d_in, const int* in_sizes, int n_in,
                              void* d_out, int out_size, void* d_ws, size_t ws_size,
                              hipStream_t stream) {
    const float* enc = (const float*)d_in[0];   // (32, 256, 384) f32
    const int*   dur = (const int*)d_in[1];     // (32, 256) i32

    float* out  = (float*)d_out;                      // (32, 384, 2048)
    float* mask = out + (size_t)Bc * Hc * Tc;         // (32, 2048)

    dim3 grid(Tc / T_PER_BLOCK, Hc / H_TILE, Bc);     // (2, 24, 32) = 1536 blocks
    dim3 block(256);
    lr_fused_kernel<<<grid, block, 0, stream>>>(enc, dur, out, mask);
}

// Round 7
// 24.110 us; speedup vs baseline: 1.3366x; 1.1182x over previous
//
#include <hip/hip_runtime.h>

// LengthRegulator: B=32, L=256, H=384, T(MAX_WAVE)=2048
// out0: (B, H, T) float32 = gathered^T ; out1: (B, T) float32 mask
constexpr int Lc = 256;
constexpr int Hc = 384;
constexpr int Tc = 2048;
constexpr int Bc = 32;
constexpr int H_TILE = 16;    // 384/16 = 24 h-tiles; grid (24,32)=768 blocks, 512 thr
constexpr int PADW = 20;      // LDS row stride (floats): 16B-aligned rows for b128

typedef float floatx4 __attribute__((ext_vector_type(4)));

__global__ __launch_bounds__(512) void lr_fused_kernel(
    const float* __restrict__ enc,   // (B, L, H)
    const int*   __restrict__ dur,   // (B, L)
    float*       __restrict__ out,   // (B, H, T)
    float*       __restrict__ mask)  // (B, T)
{
    const int tid  = threadIdx.x;     // 0..511
    const int lane = tid & 63;
    const int wv   = tid >> 6;        // wave 0..7
    const int b    = blockIdx.y;
    const int h0   = blockIdx.x * H_TILE;

    __shared__ float          s_enc[Lc * PADW];  // 20 KB
    __shared__ unsigned short s_row[Tc];         // 4 KB: t -> row index
    __shared__ int            s_wtot[8];

    // ---- 1) issue enc-tile staging loads FIRST (longest latency) ----------
    // 2 passes x 512 threads x float4: rows 0..255, cols h0..h0+15
    const float* encb = enc + (size_t)b * (Lc * Hc) + h0;
    const int r  = tid >> 2;          // 0..127
    const int c4 = (tid & 3) * 4;     // 0,4,8,12
    floatx4 st[2];
#pragma unroll
    for (int p = 0; p < 2; ++p)
        st[p] = *reinterpret_cast<const floatx4*>(encb + (size_t)(r + p * 128) * Hc + c4);

    // ---- 2) duration load (first 256 threads) + pre-fill s_row with 255 ---
    int d = 0;
    if (tid < Lc) d = dur[b * Lc + tid];
    {
        uint2 f; f.x = 0x00FF00FFu; f.y = 0x00FF00FFu;
        *reinterpret_cast<uint2*>(s_row + tid * 4) = f;   // 4 ushorts/thread
    }

    // ---- 3) barrier-free wave scan of durations (waves 4..7 scan zeros) ---
    int s = d;
#pragma unroll
    for (int off = 1; off < 64; off <<= 1) {
        int t = __shfl_up(s, off);
        if (lane >= off) s += t;
    }
    if (lane == 63) s_wtot[wv] = s;

    // write staged enc tile to LDS
#pragma unroll
    for (int p = 0; p < 2; ++p) {
        float* dst = s_enc + (r + p * 128) * PADW + c4;
        dst[0] = st[p].x; dst[1] = st[p].y; dst[2] = st[p].z; dst[3] = st[p].w;
    }

    __syncthreads();  // barrier #1

    // ---- 4) cross-wave offsets + scatter row indices ----------------------
    int pre = 0, total = 0;
#pragma unroll
    for (int w = 0; w < 4; ++w) {      // only waves 0..3 hold durations
        int t = s_wtot[w];
        total += t;
        if (w < wv) pre += t;
    }
    if (tid < Lc) {
        const int csum_i = s + pre;          // inclusive csum at position tid
        const int excl   = csum_i - d;       // exclusive prefix
        int hiw = csum_i; if (hiw > Tc) hiw = Tc;
        for (int t = excl; t < hiw; ++t) s_row[t] = (unsigned short)tid;
    }

    __syncthreads();  // barrier #2

    // ---- 5) read 4 precomputed indices, wide-gather from LDS, stream out --
    const int tbase = tid * 4;               // whole T covered by one block
    ushort4 iv = *reinterpret_cast<const ushort4*>(s_row + tbase);

    const int rowoff0 = (int)iv.x * PADW;
    const int rowoff1 = (int)iv.y * PADW;
    const int rowoff2 = (int)iv.z * PADW;
    const int rowoff3 = (int)iv.w * PADW;
    const float m0 = (tbase + 0 < total) ? 1.0f : 0.0f;
    const float m1 = (tbase + 1 < total) ? 1.0f : 0.0f;
    const float m2 = (tbase + 2 < total) ? 1.0f : 0.0f;
    const float m3 = (tbase + 3 < total) ? 1.0f : 0.0f;

    float* outb = out + (size_t)b * (Hc * Tc) + (size_t)h0 * Tc + tbase;
#pragma unroll
    for (int hh0 = 0; hh0 < H_TILE; hh0 += 4) {
        // 4 x ds_read_b128: rows of the 4 t's, cols hh0..hh0+3 (16B aligned)
        floatx4 a0 = *reinterpret_cast<const floatx4*>(s_enc + rowoff0 + hh0);
        floatx4 a1 = *reinterpret_cast<const floatx4*>(s_enc + rowoff1 + hh0);
        floatx4 a2 = *reinterpret_cast<const floatx4*>(s_enc + rowoff2 + hh0);
        floatx4 a3 = *reinterpret_cast<const floatx4*>(s_enc + rowoff3 + hh0);
#pragma unroll
        for (int j = 0; j < 4; ++j) {
            floatx4 v;
            v.x = a0[j] * m0;
            v.y = a1[j] * m1;
            v.z = a2[j] * m2;
            v.w = a3[j] * m3;
            __builtin_nontemporal_store(
                v, reinterpret_cast<floatx4*>(outb + (size_t)(hh0 + j) * Tc));
        }
    }

    // ---- 6) mask (one h-tile writes it) -----------------------------------
    if (blockIdx.x == 0) {
        floatx4 m; m.x = m0; m.y = m1; m.z = m2; m.w = m3;
        __builtin_nontemporal_store(
            m, reinterpret_cast<floatx4*>(mask + (size_t)b * Tc + tbase));
    }
}

extern "C" void kernel_launch(void* const* d_in, const int* in_sizes, int n_in,
                              void* d_out, int out_size, void* d_ws, size_t ws_size,
                              hipStream_t stream) {
    const float* enc = (const float*)d_in[0];   // (32, 256, 384) f32
    const int*   dur = (const int*)d_in[1];     // (32, 256) i32

    float* out  = (float*)d_out;                      // (32, 384, 2048)
    float* mask = out + (size_t)Bc * Hc * Tc;         // (32, 2048)

    dim3 grid(Hc / H_TILE, Bc);   // (24, 32) = 768 blocks of 512 threads
    dim3 block(512);
    lr_fused_kernel<<<grid, block, 0, stream>>>(enc, dur, out, mask);
}